// Round 5
// baseline (495.749 us; speedup 1.0000x reference)
//
#include <hip/hip_runtime.h>
#include <hip/hip_fp16.h>

// ---------------------------------------------------------------------------
// DeterministicLSTMSensorBasedForwardDynamics on MI355X (gfx950) — round 13
//
// r12 post-mortem (confounded, tripwire fired): 4 waves/SIMD forced 128
// regs/wave -> 64 arch VGPRs -> hot-loop spill. FETCH 37.6->390 MB with
// WRITE only +31 MB == weight blocks spilled once, RE-READ every step
// (~2 blocks x 50 x 256 WG x 1024 thr x 16 B ~= 420 MB). More waves/SIMD is
// structurally unreachable: per-wave registers ARE the weight residency.
//
// Unifying r8-r12: all per-CU scheduling changes (ring depth, phase order,
// wave count) were null/negative. Candidate bound: XCD-AGGREGATE L2 BW.
// r8 = 32 CUs/XCD x 384 KB/step shared weights = 12.3 MB/XCD/step over
// 12.4K cyc ~= 1 KB/cyc/XCD (saturated). Fix = fewer CUs reading the shared
// weights, each doing more work per byte.
//
// Round 13 = MTILE 32 (NWG 128, NTHR 512, proven 8-wave regime):
//   * 2 M-tiles share every B-fragment -> 176 MFMAs/wave/step, 2x compute
//     per streamed byte; per-XCD L2 traffic 12.3 -> 7.7 MB/step (-38%),
//     and ~2x per-CU L2 port share (16 active CUs/XCD).
//   * regs: acc 64 AGPR + rw 16 blocks (64 AGPR) = 128 AGPR; arch ~90
//     (ring 6 slots, NSTREAM 60, 60%6==0 cross-step ring preserved).
//   * LDS: As 2x(32x360) = 46 KB + Wc 12 blocks/wave x 8 = 96 KB = 144 KB.
//   * stream/wave/step = 60 blocks: cb1 kt0..10 (44) + cb0 kt7..10 (16).
// Prediction: dur ~170-210 us, MfmaUtil ~40-55%, FETCH ~37 MB, WRITE ~1 MB,
// conflicts ~2x. Tripwire: WRITE >5 MB = spill -> confounded. Clean null
// (>=250 us) -> L2-BW theory wrong -> next lever fp8 streamed weights.
// ---------------------------------------------------------------------------

typedef _Float16 h8 __attribute__((ext_vector_type(8)));
typedef _Float16 hv4 __attribute__((ext_vector_type(4)));
typedef float f4 __attribute__((ext_vector_type(4)));

#define NB    4096
#define TSEQ  50
#define DOBS  64
#define DACT  16
#define HD    256
#define DOUT  64
#define NL    5

#define NKT   11        // K-tiles of 32 covering 352 = 80 (x) + 256 (h) + 16 pad
#define AROW  360       // LDS A-row stride in halves
#define MTILE 32
#define NWG   (NB / MTILE)   // 128
#define NTHR  512            // 8 waves

// ws layout in halves (written by repack_kernel) — unchanged from r8
#define WS_MLP   (704 * 512)
#define WS_WOUT  (WS_MLP + 640 * 512)

// LDS layout (halves): As0 | As1 | Wcache(8 waves x WCB blocks)
#define LDS_AS     (MTILE * AROW)      // 11520 per panel
#define LDS_WCOFF  (2 * LDS_AS)        // 23040
#define WCB        12                  // LDS-resident blocks per wave (cb0 kt4..6)
#define LDS_HALVES (LDS_WCOFF + 8 * WCB * 512)   // 72192
#define LDS_BYTES  (LDS_HALVES * 2)              // 144384  (<= 160 KiB)
static_assert(LDS_BYTES <= 160 * 1024, "LDS overflow");

// Streaming (consumption order through the K-loop):
//   c in [0,28):  cb1 kt0..6   (kt=c>>2, g=c&3)
//   c in [28,60): kt7..10, per kt 8 positions: (cb0 g0),(cb1 g0),(cb0 g1),...
// Strictly monotone consumption; slot c%6 refilled with (c+6)%60 at
// consumption of c. 60 % 6 == 0 -> ring persists ACROSS steps (last 6
// refills of a step fetch the next step's positions 0..5).
#define SB_P     6
#define NSTREAM  60

// Barrier that does NOT drain vmcnt: cross-wave data dependencies at the
// t-loop barrier are ds_write-only (h and x panels), covered by lgkmcnt(0).
// In-flight global loads (stream ring, x prefetch) target private VGPRs and
// are synchronized by their own vmcnt-before-use waits -> legal to keep
// flying across s_barrier.
__device__ __forceinline__ void lds_barrier() {
  asm volatile("s_waitcnt lgkmcnt(0)\n\ts_barrier" ::: "memory");
}

// stream position c -> block offset (halves) rel. to wave base (w*2*NKT*512):
//   nt_rel = g*16 + cb  ->  (nt_rel*NKT + kt)*512
__device__ constexpr int soff(int c) {
  if (c < 28) { const int g = c & 3, kt = c >> 2; return ((g * 16 + 1) * NKT + kt) * 512; }
  const int q = c - 28;
  const int kt = 7 + (q >> 3);
  const int r = q & 7;
  const int g = r >> 1, cb = r & 1;
  return ((g * 16 + cb) * NKT + kt) * 512;
}

// --------------------------- weight repack ---------------------------------
__global__ void __launch_bounds__(256) repack_kernel(
    const float* __restrict__ Wi, const float* __restrict__ Wh,
    const float* __restrict__ mlpW, const float* __restrict__ Wout,
    _Float16* __restrict__ wsW)
{
  const int gt  = blockIdx.x * 256 + threadIdx.x;
  const int gb  = gt >> 6;
  const int l   = gt & 63;
  const int l15 = l & 15;
  const int kb  = (l >> 4) * 8;
  h8 v;
  if (gb < 704) {                       // LSTM: Wcat[k][n], k<80 -> Wi, k<336 -> Wh, else 0
    const int nt = gb / NKT, kt = gb - nt * NKT;
    const int n  = nt * 16 + l15;
#pragma unroll
    for (int j = 0; j < 8; ++j) {
      const int k = kt * 32 + kb + j;
      float s = 0.f;
      if (k < 80)       s = Wi[k * 1024 + n];
      else if (k < 336) s = Wh[(k - 80) * 1024 + n];
      v[j] = (_Float16)s;
    }
  } else if (gb < 1344) {               // MLP layer weights [5][256][256]
    const int b2 = gb - 704;
    const int L  = b2 >> 7, rr = b2 & 127;
    const int nt = rr >> 3, kt = rr & 7;
    const int n  = nt * 16 + l15;
#pragma unroll
    for (int j = 0; j < 8; ++j) {
      const int k = kt * 32 + kb + j;
      v[j] = (_Float16)mlpW[(size_t)L * 65536 + k * 256 + n];
    }
  } else {                              // Wout [256][64]
    const int b3 = gb - 1344;
    const int nt = b3 >> 3, kt = b3 & 7;
    const int n  = nt * 16 + l15;
#pragma unroll
    for (int j = 0; j < 8; ++j) {
      const int k = kt * 32 + kb + j;
      v[j] = (_Float16)Wout[k * 64 + n];
    }
  }
  *(h8*)&wsW[(size_t)gb * 512 + l * 8] = v;
}

// ------------------------------ main kernel --------------------------------
__global__ void __launch_bounds__(NTHR, 2) lstm_kernel(
    const float* __restrict__ traj, const float* __restrict__ acts,
    const float* __restrict__ bh,   const float* __restrict__ mlpb,
    const float* __restrict__ bout, const _Float16* __restrict__ wsW,
    float* __restrict__ out)
{
  extern __shared__ __align__(16) _Float16 lds[];
  _Float16* As0 = lds;
  _Float16* As1 = lds + LDS_AS;
  _Float16* Wc  = lds + LDS_WCOFF;

  const int tid = threadIdx.x;
  const int w   = tid >> 6;        // wave 0..7: owns h-cols [32w, 32w+32)
  const int l   = tid & 63;
  const int l15 = l & 15;
  const int lq  = l >> 4;
  const int rbase = blockIdx.x * MTILE;

  // Zero both A panels (h starts 0; pad cols 336..359 stay 0 forever).
  for (int i = tid; i < 2 * LDS_AS; i += NTHR) lds[i] = (_Float16)0.f;

  // LDS-resident: 12 blocks/wave = (cb0, kt4..6, g0..3), j = (kt-4)*4 + g
#pragma unroll
  for (int j = 0; j < WCB; ++j) {
    const int g = j & 3, kt = 4 + (j >> 2);
    const h8 v = *(const h8*)&wsW[(size_t)((g * 16 + w * 2) * NKT + kt) * 512 + l * 8];
    *(h8*)&Wc[(w * WCB + j) * 512 + l * 8] = v;
  }

  // Register-resident: 16 blocks/wave = (cb0, kt0..3, g0..3) — AGPR-backed.
  h8 rw[16];
#pragma unroll
  for (int kt = 0; kt < 4; ++kt)
#pragma unroll
    for (int g = 0; g < 4; ++g)
      rw[kt * 4 + g] = *(const h8*)&wsW[(size_t)((g * 16 + w * 2) * NKT + kt) * 512 + l * 8];

  // Persistent cell state (2 cb x 2 m-tiles x 4 rows) + biases
  float c[2][2][4];
#pragma unroll
  for (int cb = 0; cb < 2; ++cb)
#pragma unroll
    for (int m = 0; m < 2; ++m)
#pragma unroll
      for (int r = 0; r < 4; ++r) c[cb][m][r] = 0.f;

  float bias[4][2];
#pragma unroll
  for (int g = 0; g < 4; ++g) {
    bias[g][0] = bh[g * 256 + w * 32 + l15];
    bias[g][1] = bh[g * 256 + w * 32 + 16 + l15];
  }

  __syncthreads();

  // Stage x_0 into As0 cols 0..79: every thread loads one traj float4 and
  // one acts scalar (32 rows x 16 quads / 32 rows x 16 cols).
  {
    const int r = tid >> 4, q = tid & 15;
    const float4 v = *(const float4*)&traj[(size_t)(rbase + r) * (TSEQ * DOBS) + q * 4];
    hv4 hx = { (_Float16)v.x, (_Float16)v.y, (_Float16)v.z, (_Float16)v.w };
    *(hv4*)&As0[r * AROW + q * 4] = hx;
    As0[r * AROW + 64 + q] = (_Float16)acts[(size_t)(rbase + r) * (TSEQ * DACT) + q];
  }
  __syncthreads();

  unsigned long long wbits = (unsigned long long)(const void*)wsW;

  // Persistent 6-slot stream ring. Primed once here; thereafter each step's
  // last 6 refills prime the next step (stream order periodic mod 60).
  h8 sb[SB_P];
  {
    const _Float16* wlb0 = wsW + (size_t)(w * 2 * NKT) * 512 + l * 8;
#pragma unroll
    for (int cc = 0; cc < SB_P; ++cc) sb[cc] = *(const h8*)&wlb0[soff(cc)];
  }

  auto step = [&](int t, const _Float16* buf, _Float16* nbuf) {
    // Memory clobber: stream loads can't be hoisted/CSE'd across steps and
    // rw[] can't be legally rematerialized from wsW.
    asm volatile("" : "+s"(wbits) : : "memory");
    const _Float16* wst = (const _Float16*)wbits;
    const _Float16* wlb = wst + (size_t)(w * 2 * NKT) * 512 + l * 8;

    // x(t+1): load to registers now, store to LDS at end of step.
    float4 xv; float xa;
    const bool havex = (t + 1 < TSEQ);
    if (havex) {
      const int r = tid >> 4, q = tid & 15;
      xv = *(const float4*)&traj[(size_t)(rbase + r) * (TSEQ * DOBS) + (t + 1) * DOBS + q * 4];
      xa = acts[(size_t)(rbase + r) * (TSEQ * DACT) + (t + 1) * DACT + q];
    }

    // ---------------- fused K-loop, 2 M-tiles share every B-fragment ------
    f4 acc[2][2][4];   // [m][cb][g]
#pragma unroll
    for (int m = 0; m < 2; ++m)
#pragma unroll
      for (int cb = 0; cb < 2; ++cb)
#pragma unroll
        for (int g = 0; g < 4; ++g) acc[m][cb][g] = f4{0.f, 0.f, 0.f, 0.f};

#pragma unroll
    for (int kt = 0; kt < NKT; ++kt) {
      const h8 a0 = *(const h8*)&buf[l15 * AROW + kt * 32 + lq * 8];
      const h8 a1 = *(const h8*)&buf[(16 + l15) * AROW + kt * 32 + lq * 8];
#pragma unroll
      for (int g = 0; g < 4; ++g) {
        // cb0 fragment: registers (kt<4), LDS cache (kt4..6), stream (kt7..10)
        h8 bf0;
        if (kt < 4)      bf0 = rw[kt * 4 + g];
        else if (kt < 7) bf0 = *(const h8*)&Wc[(w * WCB + (kt - 4) * 4 + g) * 512 + l * 8];
        else {
          const int c0 = 28 + (kt - 7) * 8 + g * 2;
          bf0 = sb[c0 % SB_P];
          sb[c0 % SB_P] = *(const h8*)&wlb[soff((c0 + SB_P) % NSTREAM)];
        }
        acc[0][0][g] = __builtin_amdgcn_mfma_f32_16x16x32_f16(a0, bf0, acc[0][0][g], 0, 0, 0);
        acc[1][0][g] = __builtin_amdgcn_mfma_f32_16x16x32_f16(a1, bf0, acc[1][0][g], 0, 0, 0);

        // cb1 fragment: always streamed
        const int c1 = (kt < 7) ? (kt * 4 + g) : (29 + (kt - 7) * 8 + g * 2);
        const h8 bf1 = sb[c1 % SB_P];
        sb[c1 % SB_P] = *(const h8*)&wlb[soff((c1 + SB_P) % NSTREAM)];
        acc[0][1][g] = __builtin_amdgcn_mfma_f32_16x16x32_f16(a0, bf1, acc[0][1][g], 0, 0, 0);
        acc[1][1][g] = __builtin_amdgcn_mfma_f32_16x16x32_f16(a1, bf1, acc[1][1][g], 0, 0, 0);
      }
    }

    // ---------------- cell update (fused-rcp: 5 exp + 3 rcp per chain) ----
    const float KE = -1.44269504088896f;   // -log2(e)
#pragma unroll
    for (int cb = 0; cb < 2; ++cb) {
      const int colh = 80 + w * 32 + cb * 16 + l15;
#pragma unroll
      for (int m = 0; m < 2; ++m)
#pragma unroll
        for (int r = 0; r < 4; ++r) {
          const float zi = acc[m][cb][0][r] + bias[0][cb];
          const float zf = acc[m][cb][1][r] + bias[1][cb];
          const float zg = acc[m][cb][2][r] + bias[2][cb];
          const float zo = acc[m][cb][3][r] + bias[3][cb];
          const float ei = __builtin_amdgcn_exp2f(zi * KE);
          const float ef = __builtin_amdgcn_exp2f(zf * KE);
          const float eg = __builtin_amdgcn_exp2f(zg * KE);
          const float eo = __builtin_amdgcn_exp2f(zo * KE);
          const float fg = __builtin_amdgcn_rcpf(1.f + ef);
          const float igg = zg * __builtin_amdgcn_rcpf((1.f + ei) * (1.f + eg)); // i*g
          const float cn = fg * c[cb][m][r] + igg;
          c[cb][m][r] = cn;
          const float ec = __builtin_amdgcn_exp2f(cn * KE);
          const float hn = cn * __builtin_amdgcn_rcpf((1.f + eo) * (1.f + ec)); // o*silu(c)
          nbuf[(m * 16 + lq * 4 + r) * AROW + colh] = (_Float16)hn;
        }
    }

    // Deferred x(t+1) store into nbuf cols 0..79.
    if (havex) {
      const int r = tid >> 4, q = tid & 15;
      hv4 hx = { (_Float16)xv.x, (_Float16)xv.y, (_Float16)xv.z, (_Float16)xv.w };
      *(hv4*)&nbuf[r * AROW + q * 4] = hx;
      nbuf[r * AROW + 64 + q] = (_Float16)xa;
    }
  };

#pragma unroll 1
  for (int t = 0; t < TSEQ; t += 2) {
    step(t, As0, As1);
    lds_barrier();           // LDS-only: stream ring stays in flight
    step(t + 1, As1, As0);
    lds_barrier();
  }

  // ---------------- MLP head ----------------
  // Final h in As0 cols 80..335 (TSEQ even). Move to As1 cols 0..255.
  for (int i = tid; i < MTILE * HD; i += NTHR) {
    const int r = i >> 8, cc = i & 255;
    As1[r * AROW + cc] = As0[r * AROW + 80 + cc];
  }
  __syncthreads();

#pragma unroll 1
  for (int L = 0; L < NL; ++L) {
    const _Float16* in = (L & 1) ? As0 : As1;
    _Float16*       ob = (L & 1) ? As1 : As0;
    const _Float16* wl = wsW + WS_MLP + (size_t)L * (128 * 512);
    float bcol[2];
    bcol[0] = mlpb[L * HD + w * 32 + l15];
    bcol[1] = mlpb[L * HD + w * 32 + 16 + l15];

    f4 acc[2][2];   // [m][cb]
#pragma unroll
    for (int m = 0; m < 2; ++m)
#pragma unroll
      for (int cb = 0; cb < 2; ++cb) acc[m][cb] = f4{0.f, 0.f, 0.f, 0.f};
#pragma unroll
    for (int kt = 0; kt < 8; ++kt) {
      const h8 a0 = *(const h8*)&in[l15 * AROW + kt * 32 + lq * 8];
      const h8 a1 = *(const h8*)&in[(16 + l15) * AROW + kt * 32 + lq * 8];
#pragma unroll
      for (int cb = 0; cb < 2; ++cb) {
        const h8 bf = *(const h8*)&wl[(size_t)((w * 2 + cb) * 8 + kt) * 512 + l * 8];
        acc[0][cb] = __builtin_amdgcn_mfma_f32_16x16x32_f16(a0, bf, acc[0][cb], 0, 0, 0);
        acc[1][cb] = __builtin_amdgcn_mfma_f32_16x16x32_f16(a1, bf, acc[1][cb], 0, 0, 0);
      }
    }
#pragma unroll
    for (int cb = 0; cb < 2; ++cb)
#pragma unroll
      for (int m = 0; m < 2; ++m)
#pragma unroll
        for (int r = 0; r < 4; ++r) {
          const float z = acc[m][cb][r] + bcol[cb];
          const float ez = __builtin_amdgcn_exp2f(z * -1.44269504088896f);
          ob[(m * 16 + lq * 4 + r) * AROW + w * 32 + cb * 16 + l15] =
              (_Float16)(z * __builtin_amdgcn_rcpf(1.f + ez));
        }
    __syncthreads();
  }

  // Output layer: final activations in As0 (NL=5 odd). N=64 -> waves 0..3.
  if (w < 4) {
    const _Float16* wo = wsW + WS_WOUT;
    const float bo = bout[w * 16 + l15];
    f4 acc[2];
    acc[0] = f4{0.f, 0.f, 0.f, 0.f};
    acc[1] = f4{0.f, 0.f, 0.f, 0.f};
#pragma unroll
    for (int kt = 0; kt < 8; ++kt) {
      const h8 a0 = *(const h8*)&As0[l15 * AROW + kt * 32 + lq * 8];
      const h8 a1 = *(const h8*)&As0[(16 + l15) * AROW + kt * 32 + lq * 8];
      const h8 bf = *(const h8*)&wo[(size_t)(w * 8 + kt) * 512 + l * 8];
      acc[0] = __builtin_amdgcn_mfma_f32_16x16x32_f16(a0, bf, acc[0], 0, 0, 0);
      acc[1] = __builtin_amdgcn_mfma_f32_16x16x32_f16(a1, bf, acc[1], 0, 0, 0);
    }
#pragma unroll
    for (int m = 0; m < 2; ++m)
#pragma unroll
      for (int r = 0; r < 4; ++r)
        out[(size_t)(rbase + m * 16 + lq * 4 + r) * DOUT + w * 16 + l15] = acc[m][r] + bo;
  }
}

// ------------------------------- launcher ----------------------------------
extern "C" void kernel_launch(void* const* d_in, const int* in_sizes, int n_in,
                              void* d_out, int out_size, void* d_ws, size_t ws_size,
                              hipStream_t stream)
{
  const float* traj = (const float*)d_in[0];
  const float* acts = (const float*)d_in[1];
  const float* Wi   = (const float*)d_in[2];
  const float* Wh   = (const float*)d_in[3];
  const float* bh   = (const float*)d_in[4];
  const float* mlpW = (const float*)d_in[5];
  const float* mlpb = (const float*)d_in[6];
  const float* Wout = (const float*)d_in[7];
  const float* bout = (const float*)d_in[8];
  _Float16* wsW = (_Float16*)d_ws;   // needs 1,409,024 bytes of workspace

  (void)hipFuncSetAttribute((const void*)lstm_kernel,
                            hipFuncAttributeMaxDynamicSharedMemorySize, LDS_BYTES);

  repack_kernel<<<344, 256, 0, stream>>>(Wi, Wh, mlpW, Wout, wsW);
  lstm_kernel<<<NWG, NTHR, LDS_BYTES, stream>>>(traj, acts, bh, mlpb, bout, wsW, (float*)d_out);
}